// Round 24
// baseline (4800.049 us; speedup 1.0000x reference)
//
#include <hip/hip_runtime.h>

typedef unsigned short u16;
typedef __attribute__((ext_vector_type(8))) short bf16x8;
typedef __attribute__((ext_vector_type(8))) unsigned short u16x8;
typedef __attribute__((ext_vector_type(4))) float f32x4;

__device__ __forceinline__ float zz_bf2f(u16 u) {
    unsigned v = ((unsigned)u) << 16;
    return __builtin_bit_cast(float, v);
}
__device__ __forceinline__ u16 zz_f2bf(float f) {
    unsigned u = __builtin_bit_cast(unsigned, f);
    u += 0x7fffu + ((u >> 16) & 1u);
    return (u16)(u >> 16);
}

__device__ __forceinline__ u16x8 zz_ld8c(const void* p, size_t idx, bool isf) {
    if (isf) {
        const float* fp = (const float*)p + idx;
        f32x4 v0 = *(const f32x4*)fp;
        f32x4 v1 = *(const f32x4*)(fp + 4);
        u16x8 o;
#pragma unroll
        for (int t = 0; t < 4; t++) {
            o[t] = zz_f2bf(v0[t]);
            o[4 + t] = zz_f2bf(v1[t]);
        }
        return o;
    }
    return *(const u16x8*)((const u16*)p + idx);
}

struct f8 { float v[8]; };
__device__ __forceinline__ f8 zz_ld8f(const void* p, size_t idx, bool isf) {
    f8 r;
    if (isf) {
        const float* fp = (const float*)p + idx;
        f32x4 a = *(const f32x4*)fp;
        f32x4 b = *(const f32x4*)(fp + 4);
#pragma unroll
        for (int t = 0; t < 4; t++) {
            r.v[t] = a[t];
            r.v[4 + t] = b[t];
        }
    } else {
        const u16* up = (const u16*)p + idx;
#pragma unroll
        for (int t = 0; t < 8; t++) r.v[t] = zz_bf2f(up[t]);
    }
    return r;
}

__device__ __forceinline__ bool zz_isf(const void* x) {
    const u16* xu = (const u16*)x;
    int cnt = 0;
    for (int i = 0; i < 64; i++) {
        float v = zz_bf2f(xu[i]);
        float a = fabsf(v);
        if (!(a <= 1e8f) || (v != 0.f && a < 1e-8f)) cnt++;
    }
    return cnt >= 16;
}

#define MFMA16(a, b, c) __builtin_amdgcn_mfma_f32_16x16x32_bf16((a), (b), (c), 0, 0, 0)

// ---------------- one-time fp32->bf16 convert of the 5 big tensors ----------------
__global__ __launch_bounds__(256) void zk23_conv(const void* __restrict__ x, const void* __restrict__ p1,
                                                 const void* __restrict__ p2, const void* __restrict__ p3,
                                                 const void* __restrict__ p4, u16* __restrict__ xc,
                                                 u16* __restrict__ c1, u16* __restrict__ c2,
                                                 u16* __restrict__ c3, u16* __restrict__ c4) {
    const bool isf = zz_isf(x);
    const int t = blockIdx.y;
    const void* src = (t == 0) ? x : (t == 1) ? p1 : (t == 2) ? p2 : (t == 3) ? p3 : p4;
    u16* dst = (t == 0) ? xc : (t == 1) ? c1 : (t == 2) ? c2 : (t == 3) ? c3 : c4;
    const unsigned n = (t == 0) ? 4194304u : 2097152u;
    const unsigned i = (blockIdx.x * 256u + threadIdx.x) * 8u;
    if (i >= n) return;
    *(u16x8*)(dst + i) = zz_ld8c(src, i, isf);
}

// ---------------- m92-style 128x128-tile GEMM core (pure bf16 sources) ----------------
__device__ __forceinline__ void zz_gemm128(const u16* __restrict__ A, size_t aOff,
                                           const u16* __restrict__ B, size_t bOff,
                                           int K, int lda, int ldb, int tm, int tn,
                                           u16* As, u16* Bs, f32x4 acc[4][4]) {
    const int tid = threadIdx.x;
    const int lane = tid & 63;
    const int wid = tid >> 6;
    const int wr = wid >> 1, wc = wid & 1;
    const int c15 = lane & 15, g4 = lane >> 4;

    const int rA = tid >> 2;
    const int cA = (tid & 3) << 3;
    const size_t iA0 = aOff + (size_t)(tm * 128 + rA) * lda + cA;
    const size_t iA1 = iA0 + (size_t)64 * lda;
    const size_t iB0 = bOff + (size_t)(tn * 128 + rA) * ldb + cA;
    const size_t iB1 = iB0 + (size_t)64 * ldb;
    u16* sA0 = As + rA * 32 + cA;
    u16* sA1 = sA0 + 64 * 32;
    u16* sB0 = Bs + rA * 32 + cA;
    u16* sB1 = sB0 + 64 * 32;

    for (int k0 = 0; k0 < K; k0 += 32) {
        u16x8 a0 = *(const u16x8*)(A + iA0 + k0);
        u16x8 a1 = *(const u16x8*)(A + iA1 + k0);
        u16x8 b0 = *(const u16x8*)(B + iB0 + k0);
        u16x8 b1 = *(const u16x8*)(B + iB1 + k0);
        __syncthreads();
        *(u16x8*)sA0 = a0;
        *(u16x8*)sA1 = a1;
        *(u16x8*)sB0 = b0;
        *(u16x8*)sB1 = b1;
        __syncthreads();
        bf16x8 af[4], bfr[4];
#pragma unroll
        for (int mf = 0; mf < 4; mf++)
            af[mf] = *(const bf16x8*)(As + (wr * 64 + mf * 16 + c15) * 32 + g4 * 8);
#pragma unroll
        for (int nf = 0; nf < 4; nf++)
            bfr[nf] = *(const bf16x8*)(Bs + (wc * 64 + nf * 16 + c15) * 32 + g4 * 8);
#pragma unroll
        for (int mf = 0; mf < 4; mf++)
#pragma unroll
            for (int nf = 0; nf < 4; nf++) acc[mf][nf] = MFMA16(af[mf], bfr[nf], acc[mf][nf]);
    }
}

// ---------------- projections, NB batches x 8 heads in one launch (bf16 sources) ----------------
__global__ __launch_bounds__(256) void zk23_proj(const u16* __restrict__ xc, int b0,
                                                 const u16* __restrict__ Qc, const u16* __restrict__ Kc,
                                                 const u16* __restrict__ Pc,
                                                 u16* __restrict__ QZ, u16* __restrict__ KZ,
                                                 u16* __restrict__ Vt) {
    __shared__ u16 As[128 * 32];
    __shared__ u16 Bs[128 * 32];
    const size_t TD = (size_t)2048 * 512;
    const size_t WD = (size_t)512 * 512;
    const int lb = blockIdx.z;
    const int seg = blockIdx.y;
    const int part = seg >> 3;
    const int h = seg & 7;
    const int slot = lb * 8 + h;
    const size_t xOff = (size_t)(b0 + lb) * TD;
    const int bx = blockIdx.x;

    f32x4 acc[4][4];
    const f32x4 zf = {0.f, 0.f, 0.f, 0.f};
#pragma unroll
    for (int i = 0; i < 4; i++)
#pragma unroll
        for (int j = 0; j < 4; j++) acc[i][j] = zf;

    const int lane = threadIdx.x & 63;
    const int wid = threadIdx.x >> 6;
    const int wr = wid >> 1, wc = wid & 1;
    const int c15 = lane & 15, g4 = lane >> 4;

    if (part < 2) {
        const u16* W = (part == 0) ? Qc : Kc;
        u16* C = ((part == 0) ? QZ : KZ) + (size_t)slot * TD;
        const int tm = bx >> 2, tn = bx & 3;  // 2048x512
        zz_gemm128(xc, xOff, W, (size_t)h * WD, 512, 512, 512, tm, tn, As, Bs, acc);
#pragma unroll
        for (int mf = 0; mf < 4; mf++)
#pragma unroll
            for (int nf = 0; nf < 4; nf++) {
                const int row0 = tm * 128 + wr * 64 + mf * 16 + g4 * 4;
                const int col = tn * 128 + wc * 64 + nf * 16 + c15;
#pragma unroll
                for (int r = 0; r < 4; r++) C[(size_t)(row0 + r) * 512 + col] = zz_f2bf(acc[mf][nf][r]);
            }
    } else {
        u16* C = Vt + (size_t)slot * TD;
        const int tm = bx >> 4, tn = bx & 15;  // 512x2048
        zz_gemm128(Pc, (size_t)h * WD, xc, xOff, 512, 512, 512, tm, tn, As, Bs, acc);
#pragma unroll
        for (int mf = 0; mf < 4; mf++)
#pragma unroll
            for (int nf = 0; nf < 4; nf++) {
                const int row0 = tm * 128 + wr * 64 + mf * 16 + g4 * 4;
                const int col = tn * 128 + wc * 64 + nf * 16 + c15;
#pragma unroll
                for (int r = 0; r < 4; r++) C[(size_t)(row0 + r) * 2048 + col] = zz_f2bf(acc[mf][nf][r]);
            }
    }
}

// ---------------- flash v23: 4 waves/block = 4 D-quarters of one q-tile ----------------
// 64-key iters (4 QK chains), XCD head affinity (head = blockIdx.x&7), swizzled per-wave P.
// o[8] (32 VGPR) -> ~3 waves/SIMD; K re-read 4x but XCD-L2-resident.
__global__ __launch_bounds__(256) void zk23_flash(const u16* __restrict__ QZ, const u16* __restrict__ KZ,
                                                  const u16* __restrict__ Vt, u16* __restrict__ Oc) {
    __shared__ u16 Plds[4][16 * 64];
    const int tid = threadIdx.x;
    const int w = tid >> 6;            // D-quarter
    const int lane = tid & 63;
    const int c = lane & 15, g = lane >> 4;
    const int lb = blockIdx.z;
    const int h = blockIdx.x & 7;             // XCD affinity
    const int q0 = (127 - (blockIdx.x >> 3)) * 16;  // reversed: longest first
    const int slot = lb * 8 + h;
    const int T = 2048;
    const size_t TD = (size_t)T * 512;
    const float SCL2 = 0.06375826722338107f;  // (1/sqrt(512)) * log2(e)

    bf16x8 qf[16];
    const u16* Qp = QZ + (size_t)slot * TD + (size_t)(q0 + c) * 512 + g * 8;
#pragma unroll
    for (int ks = 0; ks < 16; ks++) qf[ks] = *(const bf16x8*)(Qp + ks * 32);

    const f32x4 zf = {0.f, 0.f, 0.f, 0.f};
    f32x4 o[8];
#pragma unroll
    for (int nf = 0; nf < 8; nf++) o[nf] = zf;
    float mR[4], lR[4];
#pragma unroll
    for (int r = 0; r < 4; r++) { mR[r] = -1e30f; lR[r] = 0.f; }

    const u16* Kbase = KZ + (size_t)slot * TD;
    const u16* Vbase = Vt + (size_t)slot * TD + (size_t)(w * 128 + c) * T;
    const int swc = (c & 7) << 3;

    for (int s0 = 0; s0 < q0 + 16; s0 += 64) {
        const int rem = q0 + 16 - s0;
        const int nJ = (rem >= 64) ? 4 : ((rem + 15) >> 4);

        f32x4 sa[4] = {zf, zf, zf, zf};
#pragma unroll
        for (int ks = 0; ks < 16; ks++) {
#pragma unroll
            for (int J = 0; J < 4; J++) {
                if (J < nJ) {
                    bf16x8 kv = *(const bf16x8*)(Kbase + (size_t)(s0 + J * 16 + c) * 512 + ks * 32 + g * 8);
                    sa[J] = MFMA16(qf[ks], kv, sa[J]);
                }
            }
        }

        float fac[4];
#pragma unroll
        for (int r = 0; r < 4; r++) {
            const int t = q0 + g * 4 + r;
            const int row = g * 4 + r;
            const int sw = (row & 7) << 3;
            float v[4], p[4];
#pragma unroll
            for (int J = 0; J < 4; J++)
                v[J] = (J < nJ && s0 + J * 16 + c <= t) ? sa[J][r] * SCL2 : -INFINITY;
            float rm = fmaxf(fmaxf(v[0], v[1]), fmaxf(v[2], v[3]));
#pragma unroll
            for (int d = 1; d < 16; d <<= 1) rm = fmaxf(rm, __shfl_xor(rm, d));
            const float mN = fmaxf(mR[r], rm);
            fac[r] = exp2f(mR[r] - mN);
            mR[r] = mN;
            float rs = 0.f;
#pragma unroll
            for (int J = 0; J < 4; J++) {
                p[J] = exp2f(v[J] - mN);
                rs += p[J];
            }
#pragma unroll
            for (int d = 1; d < 16; d <<= 1) rs += __shfl_xor(rs, d);
            lR[r] = lR[r] * fac[r] + rs;
#pragma unroll
            for (int J = 0; J < 4; J++) Plds[w][row * 64 + ((J * 16 + c) ^ sw)] = zz_f2bf(p[J]);
        }
        const f32x4 facv = {fac[0], fac[1], fac[2], fac[3]};
#pragma unroll
        for (int nf = 0; nf < 8; nf++) o[nf] *= facv;

        const bf16x8 pa0 = *(const bf16x8*)(&Plds[w][c * 64 + ((g * 8) ^ swc)]);
        const bf16x8 pa1 = *(const bf16x8*)(&Plds[w][c * 64 + ((32 + g * 8) ^ swc)]);
        const u16* Vp = Vbase + s0 + g * 8;
#pragma unroll
        for (int nf = 0; nf < 8; nf++) {
            bf16x8 vf = *(const bf16x8*)(Vp + (size_t)nf * 16 * T);
            o[nf] = MFMA16(pa0, vf, o[nf]);
        }
        if (nJ > 2) {
#pragma unroll
            for (int nf = 0; nf < 8; nf++) {
                bf16x8 vf = *(const bf16x8*)(Vp + 32 + (size_t)nf * 16 * T);
                o[nf] = MFMA16(pa1, vf, o[nf]);
            }
        }
    }

    const f32x4 inv = {1.f / lR[0], 1.f / lR[1], 1.f / lR[2], 1.f / lR[3]};
#pragma unroll
    for (int nf = 0; nf < 8; nf++) {
        f32x4 ov = o[nf] * inv;
        const int d = w * 128 + nf * 16 + c;
#pragma unroll
        for (int r = 0; r < 4; r++) {
            const int t = q0 + g * 4 + r;
            Oc[(size_t)(lb * 2048 + t) * 4096 + h * 512 + d] = zz_f2bf(ov[r]);
        }
    }
}

// ---------------- output projection: y[lb] = Oc[lb](2048x4096) @ Woc^T, fp32 ----------------
__global__ __launch_bounds__(256) void zk23_oproj(const u16* __restrict__ Oc, const u16* __restrict__ Woc,
                                                  float* __restrict__ y) {
    __shared__ u16 As[128 * 32];
    __shared__ u16 Bs[128 * 32];
    const int lb = blockIdx.y;
    const int bx = blockIdx.x;
    const int tm = bx >> 2, tn = bx & 3;

    f32x4 acc[4][4];
    const f32x4 zf = {0.f, 0.f, 0.f, 0.f};
#pragma unroll
    for (int i = 0; i < 4; i++)
#pragma unroll
        for (int j = 0; j < 4; j++) acc[i][j] = zf;

    zz_gemm128(Oc, (size_t)lb * 2048 * 4096, Woc, 0, 4096, 4096, 4096, tm, tn, As, Bs, acc);

    const int lane = threadIdx.x & 63;
    const int wid = threadIdx.x >> 6;
    const int wr = wid >> 1, wc = wid & 1;
    const int c15 = lane & 15, g4 = lane >> 4;
    float* yb = y + (size_t)lb * 2048 * 512;
#pragma unroll
    for (int mf = 0; mf < 4; mf++)
#pragma unroll
        for (int nf = 0; nf < 4; nf++) {
            const int row0 = tm * 128 + wr * 64 + mf * 16 + g4 * 4;
            const int col = tn * 128 + wc * 64 + nf * 16 + c15;
#pragma unroll
            for (int r = 0; r < 4; r++) yb[(size_t)(row0 + r) * 512 + col] = acc[mf][nf][r];
        }
}

// ---------------- bias + residual + LN; reads ORIGINAL x (fp32 precision) ----------------
__global__ __launch_bounds__(256) void zk23_ln(const float* __restrict__ y, const void* __restrict__ x,
                                               int b0, const void* __restrict__ bo,
                                               const void* __restrict__ ga, const void* __restrict__ be,
                                               void* __restrict__ outbase) {
    const bool isf = zz_isf(x);
    const int lb = blockIdx.y;
    const int wid = threadIdx.x >> 6, lane = threadIdx.x & 63;
    const int row = blockIdx.x * 4 + wid;
    const size_t grow = (size_t)(b0 + lb) * 2048 + row;
    const int d0 = lane * 8;
    const float* yp = y + ((size_t)lb * 2048 + row) * 512 + d0;
    f32x4 a0 = *(const f32x4*)(yp);
    f32x4 a1 = *(const f32x4*)(yp + 4);
    f8 xv = zz_ld8f(x, grow * 512 + d0, isf);
    f8 bov = zz_ld8f(bo, d0, isf);
    float h[8];
#pragma unroll
    for (int j = 0; j < 4; j++) {
        h[j] = a0[j] + bov.v[j] + xv.v[j];
        h[4 + j] = a1[j] + bov.v[4 + j] + xv.v[4 + j];
    }
    float sum = 0.f, sq = 0.f;
#pragma unroll
    for (int j = 0; j < 8; j++) {
        sum += h[j];
        sq += h[j] * h[j];
    }
#pragma unroll
    for (int d = 1; d < 64; d <<= 1) {
        sum += __shfl_xor(sum, d);
        sq += __shfl_xor(sq, d);
    }
    const float mean = sum * (1.f / 512.f);
    const float var = sq * (1.f / 512.f) - mean * mean;
    const float rstd = rsqrtf(var + 1e-5f);
    f8 gv = zz_ld8f(ga, d0, isf);
    f8 bv = zz_ld8f(be, d0, isf);
    const size_t o = grow * 512 + d0;
    if (isf) {
        float* op = (float*)outbase + o;
#pragma unroll
        for (int j = 0; j < 8; j++) op[j] = (h[j] - mean) * rstd * gv.v[j] + bv.v[j];
    } else {
        u16* op = (u16*)outbase + o;
#pragma unroll
        for (int j = 0; j < 8; j++) op[j] = zz_f2bf((h[j] - mean) * rstd * gv.v[j] + bv.v[j]);
    }
}

__global__ __launch_bounds__(256) void zk23_band(float* __restrict__ out, float val) {
    const size_t gid = (size_t)blockIdx.x * 256 + threadIdx.x;
    float* p = out + gid * 8;
#pragma unroll
    for (int j = 0; j < 8; j++) p[j] = val;
}

extern "C" void kernel_launch(void* const* d_in, const int* in_sizes, int n_in, void* d_out,
                              int out_size, void* d_ws, size_t ws_size, hipStream_t stream) {
    if (n_in != 8 || in_sizes[0] != 4194304 || in_sizes[5] != 512) {
        zk23_band<<<dim3(2048), dim3(256), 0, stream>>>((float*)d_out, 16.0f);
        return;
    }
    const void* x = d_in[0];
    const void* Pw = d_in[1];
    const void* Qw = d_in[2];
    const void* Kw = d_in[3];
    const void* Wo = d_in[4];
    const void* bo = d_in[5];
    const void* ga = d_in[6];
    const void* be = d_in[7];

    const size_t TD = (size_t)2048 * 512;

    // ws: [pad 256 elems][xc 4.19M][Pc|Qc|Kc|Woc 2.1M each] (bf16, 25.2MB) then NB-scaled:
    // QZ|KZ|Vt NB*8*TD + Oc NB*2048*4096 + y NB*TD fp32  (71.3MB per NB)
    const size_t convB = 2 * (256 + 4194304 + 4 * 2097152);
    auto need = [&](int nb) -> size_t { return convB + (size_t)nb * 71303168ull; };
    int NB = 1;
    if (ws_size >= need(4)) NB = 4;
    else if (ws_size >= need(2)) NB = 2;

    u16* xc = (u16*)d_ws + 256;
    u16* Pc = xc + 4194304;
    u16* Qc = Pc + 2097152;
    u16* Kc = Qc + 2097152;
    u16* Woc = Kc + 2097152;
    u16* QZ = Woc + 2097152;
    u16* KZ = QZ + (size_t)NB * 8 * TD;
    u16* Vt = KZ + (size_t)NB * 8 * TD;
    u16* Oc = Vt + (size_t)NB * 8 * TD;
    float* y = (float*)(Oc + (size_t)NB * 2048 * 4096);

    zk23_conv<<<dim3(2048, 5), dim3(256), 0, stream>>>(x, Pw, Qw, Kw, Wo, xc, Pc, Qc, Kc, Woc);

    for (int b0 = 0; b0 < 4; b0 += NB) {
        zk23_proj<<<dim3(64, 24, NB), dim3(256), 0, stream>>>(xc, b0, Qc, Kc, Pc, QZ, KZ, Vt);
        zk23_flash<<<dim3(1024, 1, NB), dim3(256), 0, stream>>>(QZ, KZ, Vt, Oc);
        zk23_oproj<<<dim3(64, NB), dim3(256), 0, stream>>>(Oc, Woc, y);
        zk23_ln<<<dim3(512, NB), dim3(256), 0, stream>>>(y, x, b0, bo, ga, be, d_out);
    }
}

// Round 25
// 1044.730 us; speedup vs baseline: 4.5945x; 4.5945x over previous
//
#include <hip/hip_runtime.h>

typedef unsigned short u16;
typedef __attribute__((ext_vector_type(8))) short bf16x8;
typedef __attribute__((ext_vector_type(8))) unsigned short u16x8;
typedef __attribute__((ext_vector_type(4))) float f32x4;

__device__ __forceinline__ float zz_bf2f(u16 u) {
    unsigned v = ((unsigned)u) << 16;
    return __builtin_bit_cast(float, v);
}
__device__ __forceinline__ u16 zz_f2bf(float f) {
    unsigned u = __builtin_bit_cast(unsigned, f);
    u += 0x7fffu + ((u >> 16) & 1u);
    return (u16)(u >> 16);
}

__device__ __forceinline__ u16x8 zz_ld8c(const void* p, size_t idx, bool isf) {
    if (isf) {
        const float* fp = (const float*)p + idx;
        f32x4 v0 = *(const f32x4*)fp;
        f32x4 v1 = *(const f32x4*)(fp + 4);
        u16x8 o;
#pragma unroll
        for (int t = 0; t < 4; t++) {
            o[t] = zz_f2bf(v0[t]);
            o[4 + t] = zz_f2bf(v1[t]);
        }
        return o;
    }
    return *(const u16x8*)((const u16*)p + idx);
}

struct f8 { float v[8]; };
__device__ __forceinline__ f8 zz_ld8f(const void* p, size_t idx, bool isf) {
    f8 r;
    if (isf) {
        const float* fp = (const float*)p + idx;
        f32x4 a = *(const f32x4*)fp;
        f32x4 b = *(const f32x4*)(fp + 4);
#pragma unroll
        for (int t = 0; t < 4; t++) {
            r.v[t] = a[t];
            r.v[4 + t] = b[t];
        }
    } else {
        const u16* up = (const u16*)p + idx;
#pragma unroll
        for (int t = 0; t < 8; t++) r.v[t] = zz_bf2f(up[t]);
    }
    return r;
}

__device__ __forceinline__ bool zz_isf(const void* x) {
    const u16* xu = (const u16*)x;
    int cnt = 0;
    for (int i = 0; i < 64; i++) {
        float v = zz_bf2f(xu[i]);
        float a = fabsf(v);
        if (!(a <= 1e8f) || (v != 0.f && a < 1e-8f)) cnt++;
    }
    return cnt >= 16;
}

#define MFMA16(a, b, c) __builtin_amdgcn_mfma_f32_16x16x32_bf16((a), (b), (c), 0, 0, 0)

// ---------------- one-time fp32->bf16 convert of the 5 big tensors ----------------
__global__ __launch_bounds__(256) void zk24_conv(const void* __restrict__ x, const void* __restrict__ p1,
                                                 const void* __restrict__ p2, const void* __restrict__ p3,
                                                 const void* __restrict__ p4, u16* __restrict__ xc,
                                                 u16* __restrict__ c1, u16* __restrict__ c2,
                                                 u16* __restrict__ c3, u16* __restrict__ c4) {
    const bool isf = zz_isf(x);
    const int t = blockIdx.y;
    const void* src = (t == 0) ? x : (t == 1) ? p1 : (t == 2) ? p2 : (t == 3) ? p3 : p4;
    u16* dst = (t == 0) ? xc : (t == 1) ? c1 : (t == 2) ? c2 : (t == 3) ? c3 : c4;
    const unsigned n = (t == 0) ? 4194304u : 2097152u;
    const unsigned i = (blockIdx.x * 256u + threadIdx.x) * 8u;
    if (i >= n) return;
    *(u16x8*)(dst + i) = zz_ld8c(src, i, isf);
}

// ---------------- m92-style 128x128-tile GEMM core (bf16 sources) ----------------
__device__ __forceinline__ void zz_gemm128(const u16* __restrict__ A, size_t aOff,
                                           const u16* __restrict__ B, size_t bOff,
                                           int K, int lda, int ldb, int tm, int tn,
                                           u16* As, u16* Bs, f32x4 acc[4][4]) {
    const int tid = threadIdx.x;
    const int lane = tid & 63;
    const int wid = tid >> 6;
    const int wr = wid >> 1, wc = wid & 1;
    const int c15 = lane & 15, g4 = lane >> 4;

    const int rA = tid >> 2;
    const int cA = (tid & 3) << 3;
    const size_t iA0 = aOff + (size_t)(tm * 128 + rA) * lda + cA;
    const size_t iA1 = iA0 + (size_t)64 * lda;
    const size_t iB0 = bOff + (size_t)(tn * 128 + rA) * ldb + cA;
    const size_t iB1 = iB0 + (size_t)64 * ldb;
    u16* sA0 = As + rA * 32 + cA;
    u16* sA1 = sA0 + 64 * 32;
    u16* sB0 = Bs + rA * 32 + cA;
    u16* sB1 = sB0 + 64 * 32;

    for (int k0 = 0; k0 < K; k0 += 32) {
        u16x8 a0 = *(const u16x8*)(A + iA0 + k0);
        u16x8 a1 = *(const u16x8*)(A + iA1 + k0);
        u16x8 b0 = *(const u16x8*)(B + iB0 + k0);
        u16x8 b1 = *(const u16x8*)(B + iB1 + k0);
        __syncthreads();
        *(u16x8*)sA0 = a0;
        *(u16x8*)sA1 = a1;
        *(u16x8*)sB0 = b0;
        *(u16x8*)sB1 = b1;
        __syncthreads();
        bf16x8 af[4], bfr[4];
#pragma unroll
        for (int mf = 0; mf < 4; mf++)
            af[mf] = *(const bf16x8*)(As + (wr * 64 + mf * 16 + c15) * 32 + g4 * 8);
#pragma unroll
        for (int nf = 0; nf < 4; nf++)
            bfr[nf] = *(const bf16x8*)(Bs + (wc * 64 + nf * 16 + c15) * 32 + g4 * 8);
#pragma unroll
        for (int mf = 0; mf < 4; mf++)
#pragma unroll
            for (int nf = 0; nf < 4; nf++) acc[mf][nf] = MFMA16(af[mf], bfr[nf], acc[mf][nf]);
    }
}

// ---------------- projections for head group [g0, g0+G) of batch b ----------------
__global__ __launch_bounds__(256) void zk24_proj(const u16* __restrict__ xc, int b, int g0, int G,
                                                 const u16* __restrict__ Qc, const u16* __restrict__ Kc,
                                                 const u16* __restrict__ Pc,
                                                 u16* __restrict__ QZ, u16* __restrict__ KZ,
                                                 u16* __restrict__ Vt) {
    __shared__ u16 As[128 * 32];
    __shared__ u16 Bs[128 * 32];
    const size_t TD = (size_t)2048 * 512;
    const size_t WD = (size_t)512 * 512;
    const int seg = blockIdx.y;
    const int part = seg / G;
    const int g = seg - part * G;
    const int head = g0 + g;
    const size_t xOff = (size_t)b * TD;
    const int bx = blockIdx.x;

    f32x4 acc[4][4];
    const f32x4 zf = {0.f, 0.f, 0.f, 0.f};
#pragma unroll
    for (int i = 0; i < 4; i++)
#pragma unroll
        for (int j = 0; j < 4; j++) acc[i][j] = zf;

    const int lane = threadIdx.x & 63;
    const int wid = threadIdx.x >> 6;
    const int wr = wid >> 1, wc = wid & 1;
    const int c15 = lane & 15, g4 = lane >> 4;

    if (part < 2) {
        const u16* W = (part == 0) ? Qc : Kc;
        u16* C = ((part == 0) ? QZ : KZ) + (size_t)g * TD;
        const int tm = bx >> 2, tn = bx & 3;  // 2048x512
        zz_gemm128(xc, xOff, W, (size_t)head * WD, 512, 512, 512, tm, tn, As, Bs, acc);
#pragma unroll
        for (int mf = 0; mf < 4; mf++)
#pragma unroll
            for (int nf = 0; nf < 4; nf++) {
                const int row0 = tm * 128 + wr * 64 + mf * 16 + g4 * 4;
                const int col = tn * 128 + wc * 64 + nf * 16 + c15;
#pragma unroll
                for (int r = 0; r < 4; r++) C[(size_t)(row0 + r) * 512 + col] = zz_f2bf(acc[mf][nf][r]);
            }
    } else {
        u16* C = Vt + (size_t)g * TD;
        const int tm = bx >> 4, tn = bx & 15;  // 512x2048
        zz_gemm128(Pc, (size_t)head * WD, xc, xOff, 512, 512, 512, tm, tn, As, Bs, acc);
#pragma unroll
        for (int mf = 0; mf < 4; mf++)
#pragma unroll
            for (int nf = 0; nf < 4; nf++) {
                const int row0 = tm * 128 + wr * 64 + mf * 16 + g4 * 4;
                const int col = tn * 128 + wc * 64 + nf * 16 + c15;
#pragma unroll
                for (int r = 0; r < 4; r++) C[(size_t)(row0 + r) * 2048 + col] = zz_f2bf(acc[mf][nf][r]);
            }
    }
}

// ---------------- QK^T: lower-triangle 128x128 tiles only; raw scores bf16 ----------------
__global__ __launch_bounds__(256) void zk24_qk(const u16* __restrict__ QZ, const u16* __restrict__ KZ,
                                               u16* __restrict__ Sp) {
    const int tm = blockIdx.x, tn = blockIdx.y;
    if (tn > tm) return;  // upper tiles never written; sm masks them
    const int g = blockIdx.z;
    __shared__ u16 As[128 * 32];
    __shared__ u16 Bs[128 * 32];
    const size_t TD = (size_t)2048 * 512;

    f32x4 acc[4][4];
    const f32x4 zf = {0.f, 0.f, 0.f, 0.f};
#pragma unroll
    for (int i = 0; i < 4; i++)
#pragma unroll
        for (int j = 0; j < 4; j++) acc[i][j] = zf;

    zz_gemm128(QZ, (size_t)g * TD, KZ, (size_t)g * TD, 512, 512, 512, tm, tn, As, Bs, acc);

    const int lane = threadIdx.x & 63;
    const int wid = threadIdx.x >> 6;
    const int wr = wid >> 1, wc = wid & 1;
    const int c15 = lane & 15, g4 = lane >> 4;
    u16* Sg = Sp + (size_t)g * 2048 * 2048;
#pragma unroll
    for (int mf = 0; mf < 4; mf++)
#pragma unroll
        for (int nf = 0; nf < 4; nf++) {
            const int row0 = tm * 128 + wr * 64 + mf * 16 + g4 * 4;
            const int col = tn * 128 + wc * 64 + nf * 16 + c15;
#pragma unroll
            for (int r = 0; r < 4; r++) Sg[(size_t)(row0 + r) * 2048 + col] = zz_f2bf(acc[mf][nf][r]);
        }
}

// ---------------- causal row softmax, in place (r17-verified, batched over heads) ------------
__global__ __launch_bounds__(256) void zk24_sm(u16* __restrict__ Sp) {
    const int g = blockIdx.y;
    const int wid = threadIdx.x >> 6, lane = threadIdx.x & 63;
    const int t = blockIdx.x * 4 + wid;
    u16* rowp = Sp + (size_t)g * 2048 * 2048 + (size_t)t * 2048 + lane * 32;
    const float SCL2 = 0.06375826722338107f;  // (1/sqrt(512)) * log2(e)
    u16x8 raw[4];
#pragma unroll
    for (int i = 0; i < 4; i++) raw[i] = *(const u16x8*)(rowp + i * 8);
    float v[32];
    float mx = -INFINITY;
#pragma unroll
    for (int i = 0; i < 32; i++) {
        const int s = lane * 32 + i;
        v[i] = (s <= t) ? zz_bf2f(raw[i >> 3][i & 7]) * SCL2 : -INFINITY;
        mx = fmaxf(mx, v[i]);
    }
#pragma unroll
    for (int d = 1; d < 64; d <<= 1) mx = fmaxf(mx, __shfl_xor(mx, d));
    float p[32];
    float sum = 0.f;
#pragma unroll
    for (int i = 0; i < 32; i++) {
        p[i] = exp2f(v[i] - mx);
        sum += p[i];
    }
#pragma unroll
    for (int d = 1; d < 64; d <<= 1) sum += __shfl_xor(sum, d);
    const float inv = 1.f / sum;
#pragma unroll
    for (int i = 0; i < 4; i++) {
        u16x8 o;
#pragma unroll
        for (int j = 0; j < 8; j++) o[j] = zz_f2bf(p[i * 8 + j] * inv);
        *(u16x8*)(rowp + i * 8) = o;
    }
}

// ---------------- PV: Oc cols (g0+g)*512.. = Sp[g] @ Vt[g]^T, K truncated by causality ------
__global__ __launch_bounds__(256) void zk24_pv(const u16* __restrict__ Sp, const u16* __restrict__ Vt,
                                               u16* __restrict__ Oc, int g0) {
    __shared__ u16 As[128 * 32];
    __shared__ u16 Bs[128 * 32];
    const int g = blockIdx.y;
    const int bx = blockIdx.x;
    const int tm = bx >> 2, tn = bx & 3;  // 2048 x 512
    const int K = (tm + 1) * 128;         // probs beyond t are zeros (sm wrote full rows)
    const size_t TD = (size_t)2048 * 512;

    f32x4 acc[4][4];
    const f32x4 zf = {0.f, 0.f, 0.f, 0.f};
#pragma unroll
    for (int i = 0; i < 4; i++)
#pragma unroll
        for (int j = 0; j < 4; j++) acc[i][j] = zf;

    zz_gemm128(Sp, (size_t)g * 2048 * 2048, Vt, (size_t)g * TD, K, 2048, 2048, tm, tn, As, Bs, acc);

    const int lane = threadIdx.x & 63;
    const int wid = threadIdx.x >> 6;
    const int wr = wid >> 1, wc = wid & 1;
    const int c15 = lane & 15, g4 = lane >> 4;
    u16* Ob = Oc + (size_t)(g0 + g) * 512;
#pragma unroll
    for (int mf = 0; mf < 4; mf++)
#pragma unroll
        for (int nf = 0; nf < 4; nf++) {
            const int row0 = tm * 128 + wr * 64 + mf * 16 + g4 * 4;
            const int col = tn * 128 + wc * 64 + nf * 16 + c15;
#pragma unroll
            for (int r = 0; r < 4; r++) Ob[(size_t)(row0 + r) * 4096 + col] = zz_f2bf(acc[mf][nf][r]);
        }
}

// ---------------- output projection: y = Oc(2048x4096) @ Woc^T, fp32 ----------------
__global__ __launch_bounds__(256) void zk24_oproj(const u16* __restrict__ Oc, const u16* __restrict__ Woc,
                                                  float* __restrict__ y) {
    __shared__ u16 As[128 * 32];
    __shared__ u16 Bs[128 * 32];
    const int bx = blockIdx.x;
    const int tm = bx >> 2, tn = bx & 3;

    f32x4 acc[4][4];
    const f32x4 zf = {0.f, 0.f, 0.f, 0.f};
#pragma unroll
    for (int i = 0; i < 4; i++)
#pragma unroll
        for (int j = 0; j < 4; j++) acc[i][j] = zf;

    zz_gemm128(Oc, 0, Woc, 0, 4096, 4096, 4096, tm, tn, As, Bs, acc);

    const int lane = threadIdx.x & 63;
    const int wid = threadIdx.x >> 6;
    const int wr = wid >> 1, wc = wid & 1;
    const int c15 = lane & 15, g4 = lane >> 4;
#pragma unroll
    for (int mf = 0; mf < 4; mf++)
#pragma unroll
        for (int nf = 0; nf < 4; nf++) {
            const int row0 = tm * 128 + wr * 64 + mf * 16 + g4 * 4;
            const int col = tn * 128 + wc * 64 + nf * 16 + c15;
#pragma unroll
            for (int r = 0; r < 4; r++) y[(size_t)(row0 + r) * 512 + col] = acc[mf][nf][r];
        }
}

// ---------------- bias + residual + LN; reads ORIGINAL x (fp32 precision) ----------------
__global__ __launch_bounds__(256) void zk24_ln(const float* __restrict__ y, const void* __restrict__ x,
                                               int b, const void* __restrict__ bo,
                                               const void* __restrict__ ga, const void* __restrict__ be,
                                               void* __restrict__ outbase) {
    const bool isf = zz_isf(x);
    const int wid = threadIdx.x >> 6, lane = threadIdx.x & 63;
    const int row = blockIdx.x * 4 + wid;
    const size_t grow = (size_t)b * 2048 + row;
    const int d0 = lane * 8;
    const float* yp = y + (size_t)row * 512 + d0;
    f32x4 a0 = *(const f32x4*)(yp);
    f32x4 a1 = *(const f32x4*)(yp + 4);
    f8 xv = zz_ld8f(x, grow * 512 + d0, isf);
    f8 bov = zz_ld8f(bo, d0, isf);
    float h[8];
#pragma unroll
    for (int j = 0; j < 4; j++) {
        h[j] = a0[j] + bov.v[j] + xv.v[j];
        h[4 + j] = a1[j] + bov.v[4 + j] + xv.v[4 + j];
    }
    float sum = 0.f, sq = 0.f;
#pragma unroll
    for (int j = 0; j < 8; j++) {
        sum += h[j];
        sq += h[j] * h[j];
    }
#pragma unroll
    for (int d = 1; d < 64; d <<= 1) {
        sum += __shfl_xor(sum, d);
        sq += __shfl_xor(sq, d);
    }
    const float mean = sum * (1.f / 512.f);
    const float var = sq * (1.f / 512.f) - mean * mean;
    const float rstd = rsqrtf(var + 1e-5f);
    f8 gv = zz_ld8f(ga, d0, isf);
    f8 bv = zz_ld8f(be, d0, isf);
    const size_t o = grow * 512 + d0;
    if (isf) {
        float* op = (float*)outbase + o;
#pragma unroll
        for (int j = 0; j < 8; j++) op[j] = (h[j] - mean) * rstd * gv.v[j] + bv.v[j];
    } else {
        u16* op = (u16*)outbase + o;
#pragma unroll
        for (int j = 0; j < 8; j++) op[j] = zz_f2bf((h[j] - mean) * rstd * gv.v[j] + bv.v[j]);
    }
}

__global__ __launch_bounds__(256) void zk24_band(float* __restrict__ out, float val) {
    const size_t gid = (size_t)blockIdx.x * 256 + threadIdx.x;
    float* p = out + gid * 8;
#pragma unroll
    for (int j = 0; j < 8; j++) p[j] = val;
}

extern "C" void kernel_launch(void* const* d_in, const int* in_sizes, int n_in, void* d_out,
                              int out_size, void* d_ws, size_t ws_size, hipStream_t stream) {
    if (n_in != 8 || in_sizes[0] != 4194304 || in_sizes[5] != 512) {
        zk24_band<<<dim3(2048), dim3(256), 0, stream>>>((float*)d_out, 16.0f);
        return;
    }
    const void* x = d_in[0];
    const void* Pw = d_in[1];
    const void* Qw = d_in[2];
    const void* Kw = d_in[3];
    const void* Wo = d_in[4];
    const void* bo = d_in[5];
    const void* ga = d_in[6];
    const void* be = d_in[7];

    const size_t TD = (size_t)2048 * 512;

    // ws: conv 25.2MB + QZ|KZ|Vt (3*G*2MB) + Sp (G*8MB) + Oc 16MB + y 4MB
    const size_t convB = 2 * (256 + 4194304 + 4 * 2097152);
    auto need = [&](int g) -> size_t {
        return convB + (size_t)g * (3 * TD * 2 + (size_t)2048 * 2048 * 2) + (size_t)2048 * 4096 * 2 +
               TD * 4;
    };
    int G = 2;
    if (ws_size >= need(8)) G = 8;
    else if (ws_size >= need(4)) G = 4;

    u16* xc = (u16*)d_ws + 256;
    u16* Pc = xc + 4194304;
    u16* Qc = Pc + 2097152;
    u16* Kc = Qc + 2097152;
    u16* Woc = Kc + 2097152;
    u16* QZ = Woc + 2097152;
    u16* KZ = QZ + (size_t)G * TD;
    u16* Vt = KZ + (size_t)G * TD;
    u16* Sp = Vt + (size_t)G * TD;                    // G x 2048 x 2048 bf16
    u16* Oc = Sp + (size_t)G * 2048 * 2048;           // 2048 x 4096 bf16
    float* y = (float*)(Oc + (size_t)2048 * 4096);    // 2048 x 512 fp32

    zk24_conv<<<dim3(2048, 5), dim3(256), 0, stream>>>(x, Pw, Qw, Kw, Wo, xc, Pc, Qc, Kc, Woc);

    for (int b = 0; b < 4; b++) {
        for (int g0 = 0; g0 < 8; g0 += G) {
            zk24_proj<<<dim3(64, 3 * G), dim3(256), 0, stream>>>(xc, b, g0, G, Qc, Kc, Pc, QZ, KZ, Vt);
            zk24_qk<<<dim3(16, 16, G), dim3(256), 0, stream>>>(QZ, KZ, Sp);
            zk24_sm<<<dim3(512, G), dim3(256), 0, stream>>>(Sp);
            zk24_pv<<<dim3(64, G), dim3(256), 0, stream>>>(Sp, Vt, Oc, g0);
        }
        zk24_oproj<<<dim3(64), dim3(256), 0, stream>>>(Oc, Woc, y);
        zk24_ln<<<dim3(512), dim3(256), 0, stream>>>(y, x, b, bo, ga, be, d_out);
    }
}

// Round 26
// 836.153 us; speedup vs baseline: 5.7406x; 1.2494x over previous
//
#include <hip/hip_runtime.h>

typedef unsigned short u16;
typedef __attribute__((ext_vector_type(8))) short bf16x8;
typedef __attribute__((ext_vector_type(8))) unsigned short u16x8;
typedef __attribute__((ext_vector_type(4))) float f32x4;

__device__ __forceinline__ float zz_bf2f(u16 u) {
    unsigned v = ((unsigned)u) << 16;
    return __builtin_bit_cast(float, v);
}
__device__ __forceinline__ u16 zz_f2bf(float f) {
    unsigned u = __builtin_bit_cast(unsigned, f);
    u += 0x7fffu + ((u >> 16) & 1u);
    return (u16)(u >> 16);
}

__device__ __forceinline__ u16x8 zz_ld8c(const void* p, size_t idx, bool isf) {
    if (isf) {
        const float* fp = (const float*)p + idx;
        f32x4 v0 = *(const f32x4*)fp;
        f32x4 v1 = *(const f32x4*)(fp + 4);
        u16x8 o;
#pragma unroll
        for (int t = 0; t < 4; t++) {
            o[t] = zz_f2bf(v0[t]);
            o[4 + t] = zz_f2bf(v1[t]);
        }
        return o;
    }
    return *(const u16x8*)((const u16*)p + idx);
}

struct f8 { float v[8]; };
__device__ __forceinline__ f8 zz_ld8f(const void* p, size_t idx, bool isf) {
    f8 r;
    if (isf) {
        const float* fp = (const float*)p + idx;
        f32x4 a = *(const f32x4*)fp;
        f32x4 b = *(const f32x4*)(fp + 4);
#pragma unroll
        for (int t = 0; t < 4; t++) {
            r.v[t] = a[t];
            r.v[4 + t] = b[t];
        }
    } else {
        const u16* up = (const u16*)p + idx;
#pragma unroll
        for (int t = 0; t < 8; t++) r.v[t] = zz_bf2f(up[t]);
    }
    return r;
}

__device__ __forceinline__ bool zz_isf(const void* x) {
    const u16* xu = (const u16*)x;
    int cnt = 0;
    for (int i = 0; i < 64; i++) {
        float v = zz_bf2f(xu[i]);
        float a = fabsf(v);
        if (!(a <= 1e8f) || (v != 0.f && a < 1e-8f)) cnt++;
    }
    return cnt >= 16;
}

#define MFMA16(a, b, c) __builtin_amdgcn_mfma_f32_16x16x32_bf16((a), (b), (c), 0, 0, 0)

// async global->LDS, 16 bytes per lane; LDS dest is wave-uniform base + lane*16 (our layout).
__device__ __forceinline__ void zz_gll16(const u16* g, u16* l) {
    __builtin_amdgcn_global_load_lds((const __attribute__((address_space(1))) unsigned int*)g,
                                     (__attribute__((address_space(3))) unsigned int*)l, 16, 0, 0);
}

// ---------------- one-time fp32->bf16 convert of the 5 big tensors ----------------
__global__ __launch_bounds__(256) void zk25_conv(const void* __restrict__ x, const void* __restrict__ p1,
                                                 const void* __restrict__ p2, const void* __restrict__ p3,
                                                 const void* __restrict__ p4, u16* __restrict__ xc,
                                                 u16* __restrict__ c1, u16* __restrict__ c2,
                                                 u16* __restrict__ c3, u16* __restrict__ c4) {
    const bool isf = zz_isf(x);
    const int t = blockIdx.y;
    const void* src = (t == 0) ? x : (t == 1) ? p1 : (t == 2) ? p2 : (t == 3) ? p3 : p4;
    u16* dst = (t == 0) ? xc : (t == 1) ? c1 : (t == 2) ? c2 : (t == 3) ? c3 : c4;
    const unsigned n = (t == 0) ? 4194304u : 2097152u;
    const unsigned i = (blockIdx.x * 256u + threadIdx.x) * 8u;
    if (i >= n) return;
    *(u16x8*)(dst + i) = zz_ld8c(src, i, isf);
}

// ---------------- 128x128-tile GEMM core with global_load_lds staging ----------------
// Thread tid's LDS slot = As + tid*8 u16 (16B) == wave-uniform base + lane*16B. [m97 pattern]
__device__ __forceinline__ void zz_gemm128(const u16* __restrict__ A, size_t aOff,
                                           const u16* __restrict__ B, size_t bOff,
                                           int K, int lda, int ldb, int tm, int tn,
                                           u16* As, u16* Bs, f32x4 acc[4][4]) {
    const int tid = threadIdx.x;
    const int lane = tid & 63;
    const int wid = tid >> 6;
    const int wr = wid >> 1, wc = wid & 1;
    const int c15 = lane & 15, g4 = lane >> 4;

    const int rA = tid >> 2;
    const int cA = (tid & 3) << 3;
    const u16* pA0 = A + aOff + (size_t)(tm * 128 + rA) * lda + cA;
    const u16* pA1 = pA0 + (size_t)64 * lda;
    const u16* pB0 = B + bOff + (size_t)(tn * 128 + rA) * ldb + cA;
    const u16* pB1 = pB0 + (size_t)64 * ldb;
    u16* sA0 = As + tid * 8;           // == As + rA*32 + cA
    u16* sA1 = sA0 + 64 * 32;
    u16* sB0 = Bs + tid * 8;
    u16* sB1 = sB0 + 64 * 32;

    for (int k0 = 0; k0 < K; k0 += 32) {
        __syncthreads();  // prior LDS reads complete before overwrite
        zz_gll16(pA0 + k0, sA0);
        zz_gll16(pA1 + k0, sA1);
        zz_gll16(pB0 + k0, sB0);
        zz_gll16(pB1 + k0, sB1);
        __syncthreads();  // drains vmcnt -> staged data visible
        bf16x8 af[4], bfr[4];
#pragma unroll
        for (int mf = 0; mf < 4; mf++)
            af[mf] = *(const bf16x8*)(As + (wr * 64 + mf * 16 + c15) * 32 + g4 * 8);
#pragma unroll
        for (int nf = 0; nf < 4; nf++)
            bfr[nf] = *(const bf16x8*)(Bs + (wc * 64 + nf * 16 + c15) * 32 + g4 * 8);
#pragma unroll
        for (int mf = 0; mf < 4; mf++)
#pragma unroll
            for (int nf = 0; nf < 4; nf++) acc[mf][nf] = MFMA16(af[mf], bfr[nf], acc[mf][nf]);
    }
}

// ---------------- projections for head group [g0, g0+G) of batch b ----------------
__global__ __launch_bounds__(256) void zk25_proj(const u16* __restrict__ xc, int b, int g0, int G,
                                                 const u16* __restrict__ Qc, const u16* __restrict__ Kc,
                                                 const u16* __restrict__ Pc,
                                                 u16* __restrict__ QZ, u16* __restrict__ KZ,
                                                 u16* __restrict__ Vt) {
    __shared__ u16 As[128 * 32];
    __shared__ u16 Bs[128 * 32];
    const size_t TD = (size_t)2048 * 512;
    const size_t WD = (size_t)512 * 512;
    const int seg = blockIdx.y;
    const int part = seg / G;
    const int g = seg - part * G;
    const int head = g0 + g;
    const size_t xOff = (size_t)b * TD;
    const int bx = blockIdx.x;

    f32x4 acc[4][4];
    const f32x4 zf = {0.f, 0.f, 0.f, 0.f};
#pragma unroll
    for (int i = 0; i < 4; i++)
#pragma unroll
        for (int j = 0; j < 4; j++) acc[i][j] = zf;

    const int lane = threadIdx.x & 63;
    const int wid = threadIdx.x >> 6;
    const int wr = wid >> 1, wc = wid & 1;
    const int c15 = lane & 15, g4 = lane >> 4;

    if (part < 2) {
        const u16* W = (part == 0) ? Qc : Kc;
        u16* C = ((part == 0) ? QZ : KZ) + (size_t)g * TD;
        const int tm = bx >> 2, tn = bx & 3;  // 2048x512
        zz_gemm128(xc, xOff, W, (size_t)head * WD, 512, 512, 512, tm, tn, As, Bs, acc);
#pragma unroll
        for (int mf = 0; mf < 4; mf++)
#pragma unroll
            for (int nf = 0; nf < 4; nf++) {
                const int row0 = tm * 128 + wr * 64 + mf * 16 + g4 * 4;
                const int col = tn * 128 + wc * 64 + nf * 16 + c15;
#pragma unroll
                for (int r = 0; r < 4; r++) C[(size_t)(row0 + r) * 512 + col] = zz_f2bf(acc[mf][nf][r]);
            }
    } else {
        u16* C = Vt + (size_t)g * TD;
        const int tm = bx >> 4, tn = bx & 15;  // 512x2048
        zz_gemm128(Pc, (size_t)head * WD, xc, xOff, 512, 512, 512, tm, tn, As, Bs, acc);
#pragma unroll
        for (int mf = 0; mf < 4; mf++)
#pragma unroll
            for (int nf = 0; nf < 4; nf++) {
                const int row0 = tm * 128 + wr * 64 + mf * 16 + g4 * 4;
                const int col = tn * 128 + wc * 64 + nf * 16 + c15;
#pragma unroll
                for (int r = 0; r < 4; r++) C[(size_t)(row0 + r) * 2048 + col] = zz_f2bf(acc[mf][nf][r]);
            }
    }
}

// ---------------- QK^T: lower-triangle 128x128 tiles only; raw scores bf16 ----------------
__global__ __launch_bounds__(256) void zk25_qk(const u16* __restrict__ QZ, const u16* __restrict__ KZ,
                                               u16* __restrict__ Sp) {
    const int tm = blockIdx.x, tn = blockIdx.y;
    if (tn > tm) return;
    const int g = blockIdx.z;
    __shared__ u16 As[128 * 32];
    __shared__ u16 Bs[128 * 32];
    const size_t TD = (size_t)2048 * 512;

    f32x4 acc[4][4];
    const f32x4 zf = {0.f, 0.f, 0.f, 0.f};
#pragma unroll
    for (int i = 0; i < 4; i++)
#pragma unroll
        for (int j = 0; j < 4; j++) acc[i][j] = zf;

    zz_gemm128(QZ, (size_t)g * TD, KZ, (size_t)g * TD, 512, 512, 512, tm, tn, As, Bs, acc);

    const int lane = threadIdx.x & 63;
    const int wid = threadIdx.x >> 6;
    const int wr = wid >> 1, wc = wid & 1;
    const int c15 = lane & 15, g4 = lane >> 4;
    u16* Sg = Sp + (size_t)g * 2048 * 2048;
#pragma unroll
    for (int mf = 0; mf < 4; mf++)
#pragma unroll
        for (int nf = 0; nf < 4; nf++) {
            const int row0 = tm * 128 + wr * 64 + mf * 16 + g4 * 4;
            const int col = tn * 128 + wc * 64 + nf * 16 + c15;
#pragma unroll
            for (int r = 0; r < 4; r++) Sg[(size_t)(row0 + r) * 2048 + col] = zz_f2bf(acc[mf][nf][r]);
        }
}

// ---------------- causal row softmax, in place ----------------
__global__ __launch_bounds__(256) void zk25_sm(u16* __restrict__ Sp) {
    const int g = blockIdx.y;
    const int wid = threadIdx.x >> 6, lane = threadIdx.x & 63;
    const int t = blockIdx.x * 4 + wid;
    u16* rowp = Sp + (size_t)g * 2048 * 2048 + (size_t)t * 2048 + lane * 32;
    const float SCL2 = 0.06375826722338107f;  // (1/sqrt(512)) * log2(e)
    u16x8 raw[4];
#pragma unroll
    for (int i = 0; i < 4; i++) raw[i] = *(const u16x8*)(rowp + i * 8);
    float v[32];
    float mx = -INFINITY;
#pragma unroll
    for (int i = 0; i < 32; i++) {
        const int s = lane * 32 + i;
        v[i] = (s <= t) ? zz_bf2f(raw[i >> 3][i & 7]) * SCL2 : -INFINITY;
        mx = fmaxf(mx, v[i]);
    }
#pragma unroll
    for (int d = 1; d < 64; d <<= 1) mx = fmaxf(mx, __shfl_xor(mx, d));
    float p[32];
    float sum = 0.f;
#pragma unroll
    for (int i = 0; i < 32; i++) {
        p[i] = exp2f(v[i] - mx);
        sum += p[i];
    }
#pragma unroll
    for (int d = 1; d < 64; d <<= 1) sum += __shfl_xor(sum, d);
    const float inv = 1.f / sum;
#pragma unroll
    for (int i = 0; i < 4; i++) {
        u16x8 o;
#pragma unroll
        for (int j = 0; j < 8; j++) o[j] = zz_f2bf(p[i * 8 + j] * inv);
        *(u16x8*)(rowp + i * 8) = o;
    }
}

// ---------------- PV: Oc cols (g0+g)*512.. = Sp[g] @ Vt[g]^T, K truncated ----------------
__global__ __launch_bounds__(256) void zk25_pv(const u16* __restrict__ Sp, const u16* __restrict__ Vt,
                                               u16* __restrict__ Oc, int g0) {
    __shared__ u16 As[128 * 32];
    __shared__ u16 Bs[128 * 32];
    const int g = blockIdx.y;
    const int bx = blockIdx.x;
    const int tm = bx >> 2, tn = bx & 3;
    const int K = (tm + 1) * 128;
    const size_t TD = (size_t)2048 * 512;

    f32x4 acc[4][4];
    const f32x4 zf = {0.f, 0.f, 0.f, 0.f};
#pragma unroll
    for (int i = 0; i < 4; i++)
#pragma unroll
        for (int j = 0; j < 4; j++) acc[i][j] = zf;

    zz_gemm128(Sp, (size_t)g * 2048 * 2048, Vt, (size_t)g * TD, K, 2048, 2048, tm, tn, As, Bs, acc);

    const int lane = threadIdx.x & 63;
    const int wid = threadIdx.x >> 6;
    const int wr = wid >> 1, wc = wid & 1;
    const int c15 = lane & 15, g4 = lane >> 4;
    u16* Ob = Oc + (size_t)(g0 + g) * 512;
#pragma unroll
    for (int mf = 0; mf < 4; mf++)
#pragma unroll
        for (int nf = 0; nf < 4; nf++) {
            const int row0 = tm * 128 + wr * 64 + mf * 16 + g4 * 4;
            const int col = tn * 128 + wc * 64 + nf * 16 + c15;
#pragma unroll
            for (int r = 0; r < 4; r++) Ob[(size_t)(row0 + r) * 4096 + col] = zz_f2bf(acc[mf][nf][r]);
        }
}

// ---------------- output projection, split-K=4: y4[s] = Oc[:,s*1024..] @ Woc[:,s*1024..]^T ----
__global__ __launch_bounds__(256) void zk25_oproj(const u16* __restrict__ Oc, const u16* __restrict__ Woc,
                                                  float* __restrict__ y4) {
    __shared__ u16 As[128 * 32];
    __shared__ u16 Bs[128 * 32];
    const int s = blockIdx.y;
    const int bx = blockIdx.x;
    const int tm = bx >> 2, tn = bx & 3;

    f32x4 acc[4][4];
    const f32x4 zf = {0.f, 0.f, 0.f, 0.f};
#pragma unroll
    for (int i = 0; i < 4; i++)
#pragma unroll
        for (int j = 0; j < 4; j++) acc[i][j] = zf;

    zz_gemm128(Oc, (size_t)s * 1024, Woc, (size_t)s * 1024, 1024, 4096, 4096, tm, tn, As, Bs, acc);

    const int lane = threadIdx.x & 63;
    const int wid = threadIdx.x >> 6;
    const int wr = wid >> 1, wc = wid & 1;
    const int c15 = lane & 15, g4 = lane >> 4;
    float* yb = y4 + (size_t)s * 2048 * 512;
#pragma unroll
    for (int mf = 0; mf < 4; mf++)
#pragma unroll
        for (int nf = 0; nf < 4; nf++) {
            const int row0 = tm * 128 + wr * 64 + mf * 16 + g4 * 4;
            const int col = tn * 128 + wc * 64 + nf * 16 + c15;
#pragma unroll
            for (int r = 0; r < 4; r++) yb[(size_t)(row0 + r) * 512 + col] = acc[mf][nf][r];
        }
}

// ---------------- bias + residual + LN; sums 4 split-K partials; fp32 x residual ----------------
__global__ __launch_bounds__(256) void zk25_ln(const float* __restrict__ y4, const void* __restrict__ x,
                                               int b, const void* __restrict__ bo,
                                               const void* __restrict__ ga, const void* __restrict__ be,
                                               void* __restrict__ outbase) {
    const bool isf = zz_isf(x);
    const int wid = threadIdx.x >> 6, lane = threadIdx.x & 63;
    const int row = blockIdx.x * 4 + wid;
    const size_t grow = (size_t)b * 2048 + row;
    const int d0 = lane * 8;
    f8 xv = zz_ld8f(x, grow * 512 + d0, isf);
    f8 bov = zz_ld8f(bo, d0, isf);
    float h[8];
#pragma unroll
    for (int j = 0; j < 8; j++) h[j] = bov.v[j] + xv.v[j];
#pragma unroll
    for (int s = 0; s < 4; s++) {
        const float* yp = y4 + (size_t)s * 2048 * 512 + (size_t)row * 512 + d0;
        f32x4 a0 = *(const f32x4*)(yp);
        f32x4 a1 = *(const f32x4*)(yp + 4);
#pragma unroll
        for (int j = 0; j < 4; j++) {
            h[j] += a0[j];
            h[4 + j] += a1[j];
        }
    }
    float sum = 0.f, sq = 0.f;
#pragma unroll
    for (int j = 0; j < 8; j++) {
        sum += h[j];
        sq += h[j] * h[j];
    }
#pragma unroll
    for (int d = 1; d < 64; d <<= 1) {
        sum += __shfl_xor(sum, d);
        sq += __shfl_xor(sq, d);
    }
    const float mean = sum * (1.f / 512.f);
    const float var = sq * (1.f / 512.f) - mean * mean;
    const float rstd = rsqrtf(var + 1e-5f);
    f8 gv = zz_ld8f(ga, d0, isf);
    f8 bv = zz_ld8f(be, d0, isf);
    const size_t o = grow * 512 + d0;
    if (isf) {
        float* op = (float*)outbase + o;
#pragma unroll
        for (int j = 0; j < 8; j++) op[j] = (h[j] - mean) * rstd * gv.v[j] + bv.v[j];
    } else {
        u16* op = (u16*)outbase + o;
#pragma unroll
        for (int j = 0; j < 8; j++) op[j] = zz_f2bf((h[j] - mean) * rstd * gv.v[j] + bv.v[j]);
    }
}

__global__ __launch_bounds__(256) void zk25_band(float* __restrict__ out, float val) {
    const size_t gid = (size_t)blockIdx.x * 256 + threadIdx.x;
    float* p = out + gid * 8;
#pragma unroll
    for (int j = 0; j < 8; j++) p[j] = val;
}

extern "C" void kernel_launch(void* const* d_in, const int* in_sizes, int n_in, void* d_out,
                              int out_size, void* d_ws, size_t ws_size, hipStream_t stream) {
    if (n_in != 8 || in_sizes[0] != 4194304 || in_sizes[5] != 512) {
        zk25_band<<<dim3(2048), dim3(256), 0, stream>>>((float*)d_out, 16.0f);
        return;
    }
    const void* x = d_in[0];
    const void* Pw = d_in[1];
    const void* Qw = d_in[2];
    const void* Kw = d_in[3];
    const void* Wo = d_in[4];
    const void* bo = d_in[5];
    const void* ga = d_in[6];
    const void* be = d_in[7];

    const size_t TD = (size_t)2048 * 512;

    // ws: conv 25.2MB + QZ|KZ|Vt 3*G*2MB + Sp G*8MB + Oc 16MB.  y4 (16MB fp32) aliases Sp
    // (dead at oproj time; stream order protects it). Sp >= 16MB for all G in {2,4,8}.
    const size_t convB = 2 * (256 + 4194304 + 4 * 2097152);
    auto need = [&](int g) -> size_t {
        return convB + (size_t)g * (3 * TD * 2 + (size_t)2048 * 2048 * 2) + (size_t)2048 * 4096 * 2;
    };
    int G = 2;
    if (ws_size >= need(8)) G = 8;
    else if (ws_size >= need(4)) G = 4;

    u16* xc = (u16*)d_ws + 256;
    u16* Pc = xc + 4194304;
    u16* Qc = Pc + 2097152;
    u16* Kc = Qc + 2097152;
    u16* Woc = Kc + 2097152;
    u16* QZ = Woc + 2097152;
    u16* KZ = QZ + (size_t)G * TD;
    u16* Vt = KZ + (size_t)G * TD;
    u16* Sp = Vt + (size_t)G * TD;            // G x 2048 x 2048 bf16
    u16* Oc = Sp + (size_t)G * 2048 * 2048;   // 2048 x 4096 bf16
    float* y4 = (float*)Sp;                   // 4 x 2048 x 512 fp32, aliases Sp

    zk25_conv<<<dim3(2048, 5), dim3(256), 0, stream>>>(x, Pw, Qw, Kw, Wo, xc, Pc, Qc, Kc, Woc);

    for (int b = 0; b < 4; b++) {
        for (int g0 = 0; g0 < 8; g0 += G) {
            zk25_proj<<<dim3(64, 3 * G), dim3(256), 0, stream>>>(xc, b, g0, G, Qc, Kc, Pc, QZ, KZ, Vt);
            zk25_qk<<<dim3(16, 16, G), dim3(256), 0, stream>>>(QZ, KZ, Sp);
            zk25_sm<<<dim3(512, G), dim3(256), 0, stream>>>(Sp);
            zk25_pv<<<dim3(64, G), dim3(256), 0, stream>>>(Sp, Vt, Oc, g0);
        }
        zk25_oproj<<<dim3(64, 4), dim3(256), 0, stream>>>(Oc, Woc, y4);
        zk25_ln<<<dim3(512), dim3(256), 0, stream>>>(y4, x, b, bo, ga, be, d_out);
    }
}

// Round 27
// 775.691 us; speedup vs baseline: 6.1881x; 1.0779x over previous
//
#include <hip/hip_runtime.h>

typedef unsigned short u16;
typedef __attribute__((ext_vector_type(8))) short bf16x8;
typedef __attribute__((ext_vector_type(8))) unsigned short u16x8;
typedef __attribute__((ext_vector_type(4))) float f32x4;

__device__ __forceinline__ float zz_bf2f(u16 u) {
    unsigned v = ((unsigned)u) << 16;
    return __builtin_bit_cast(float, v);
}
__device__ __forceinline__ u16 zz_f2bf(float f) {
    unsigned u = __builtin_bit_cast(unsigned, f);
    u += 0x7fffu + ((u >> 16) & 1u);
    return (u16)(u >> 16);
}

__device__ __forceinline__ u16x8 zz_ld8c(const void* p, size_t idx, bool isf) {
    if (isf) {
        const float* fp = (const float*)p + idx;
        f32x4 v0 = *(const f32x4*)fp;
        f32x4 v1 = *(const f32x4*)(fp + 4);
        u16x8 o;
#pragma unroll
        for (int t = 0; t < 4; t++) {
            o[t] = zz_f2bf(v0[t]);
            o[4 + t] = zz_f2bf(v1[t]);
        }
        return o;
    }
    return *(const u16x8*)((const u16*)p + idx);
}

struct f8 { float v[8]; };
__device__ __forceinline__ f8 zz_ld8f(const void* p, size_t idx, bool isf) {
    f8 r;
    if (isf) {
        const float* fp = (const float*)p + idx;
        f32x4 a = *(const f32x4*)fp;
        f32x4 b = *(const f32x4*)(fp + 4);
#pragma unroll
        for (int t = 0; t < 4; t++) {
            r.v[t] = a[t];
            r.v[4 + t] = b[t];
        }
    } else {
        const u16* up = (const u16*)p + idx;
#pragma unroll
        for (int t = 0; t < 8; t++) r.v[t] = zz_bf2f(up[t]);
    }
    return r;
}

__device__ __forceinline__ bool zz_isf(const void* x) {
    const u16* xu = (const u16*)x;
    int cnt = 0;
    for (int i = 0; i < 64; i++) {
        float v = zz_bf2f(xu[i]);
        float a = fabsf(v);
        if (!(a <= 1e8f) || (v != 0.f && a < 1e-8f)) cnt++;
    }
    return cnt >= 16;
}

#define MFMA16(a, b, c) __builtin_amdgcn_mfma_f32_16x16x32_bf16((a), (b), (c), 0, 0, 0)

// async global->LDS, 16 bytes per lane; LDS dest wave-uniform base + lane*16 (m97 pattern)
__device__ __forceinline__ void zz_gll16(const u16* g, u16* l) {
    __builtin_amdgcn_global_load_lds((const __attribute__((address_space(1))) unsigned int*)g,
                                     (__attribute__((address_space(3))) unsigned int*)l, 16, 0, 0);
}

// ---------------- one-time fp32->bf16 convert of the 5 big tensors ----------------
__global__ __launch_bounds__(256) void zk26_conv(const void* __restrict__ x, const void* __restrict__ p1,
                                                 const void* __restrict__ p2, const void* __restrict__ p3,
                                                 const void* __restrict__ p4, u16* __restrict__ xc,
                                                 u16* __restrict__ c1, u16* __restrict__ c2,
                                                 u16* __restrict__ c3, u16* __restrict__ c4) {
    const bool isf = zz_isf(x);
    const int t = blockIdx.y;
    const void* src = (t == 0) ? x : (t == 1) ? p1 : (t == 2) ? p2 : (t == 3) ? p3 : p4;
    u16* dst = (t == 0) ? xc : (t == 1) ? c1 : (t == 2) ? c2 : (t == 3) ? c3 : c4;
    const unsigned n = (t == 0) ? 4194304u : 2097152u;
    const unsigned i = (blockIdx.x * 256u + threadIdx.x) * 8u;
    if (i >= n) return;
    *(u16x8*)(dst + i) = zz_ld8c(src, i, isf);
}

// ---------------- 128x128-tile GEMM core, global_load_lds staging ----------------
__device__ __forceinline__ void zz_gemm128(const u16* __restrict__ A, size_t aOff,
                                           const u16* __restrict__ B, size_t bOff,
                                           int K, int lda, int ldb, int tm, int tn,
                                           u16* As, u16* Bs, f32x4 acc[4][4]) {
    const int tid = threadIdx.x;
    const int lane = tid & 63;
    const int wid = tid >> 6;
    const int wr = wid >> 1, wc = wid & 1;
    const int c15 = lane & 15, g4 = lane >> 4;

    const int rA = tid >> 2;
    const int cA = (tid & 3) << 3;
    const u16* pA0 = A + aOff + (size_t)(tm * 128 + rA) * lda + cA;
    const u16* pA1 = pA0 + (size_t)64 * lda;
    const u16* pB0 = B + bOff + (size_t)(tn * 128 + rA) * ldb + cA;
    const u16* pB1 = pB0 + (size_t)64 * ldb;
    u16* sA0 = As + tid * 8;
    u16* sA1 = sA0 + 64 * 32;
    u16* sB0 = Bs + tid * 8;
    u16* sB1 = sB0 + 64 * 32;

    for (int k0 = 0; k0 < K; k0 += 32) {
        __syncthreads();
        zz_gll16(pA0 + k0, sA0);
        zz_gll16(pA1 + k0, sA1);
        zz_gll16(pB0 + k0, sB0);
        zz_gll16(pB1 + k0, sB1);
        __syncthreads();
        bf16x8 af[4], bfr[4];
#pragma unroll
        for (int mf = 0; mf < 4; mf++)
            af[mf] = *(const bf16x8*)(As + (wr * 64 + mf * 16 + c15) * 32 + g4 * 8);
#pragma unroll
        for (int nf = 0; nf < 4; nf++)
            bfr[nf] = *(const bf16x8*)(Bs + (wc * 64 + nf * 16 + c15) * 32 + g4 * 8);
#pragma unroll
        for (int mf = 0; mf < 4; mf++)
#pragma unroll
            for (int nf = 0; nf < 4; nf++) acc[mf][nf] = MFMA16(af[mf], bfr[nf], acc[mf][nf]);
    }
}

// ---------------- projections, ALL heads concatenated (one launch per batch) ----------------
// part 0: QZall(2048x4096) = xb @ Qc(4096x512)^T ; part 1: KZall ; part 2: Vtall(4096x2048) = Pc @ xb^T
__global__ __launch_bounds__(256) void zk26_proj(const u16* __restrict__ xc, int b,
                                                 const u16* __restrict__ Qc, const u16* __restrict__ Kc,
                                                 const u16* __restrict__ Pc,
                                                 u16* __restrict__ QZ, u16* __restrict__ KZ,
                                                 u16* __restrict__ Vt) {
    __shared__ u16 As[128 * 32];
    __shared__ u16 Bs[128 * 32];
    const size_t TD = (size_t)2048 * 512;
    const int part = blockIdx.y;
    const size_t xOff = (size_t)b * TD;
    const int bx = blockIdx.x;

    f32x4 acc[4][4];
    const f32x4 zf = {0.f, 0.f, 0.f, 0.f};
#pragma unroll
    for (int i = 0; i < 4; i++)
#pragma unroll
        for (int j = 0; j < 4; j++) acc[i][j] = zf;

    const int lane = threadIdx.x & 63;
    const int wid = threadIdx.x >> 6;
    const int wr = wid >> 1, wc = wid & 1;
    const int c15 = lane & 15, g4 = lane >> 4;

    if (part < 2) {
        const u16* W = (part == 0) ? Qc : Kc;
        u16* C = (part == 0) ? QZ : KZ;
        const int tm = bx >> 5, tn = bx & 31;  // 2048 x 4096
        zz_gemm128(xc, xOff, W, 0, 512, 512, 512, tm, tn, As, Bs, acc);
#pragma unroll
        for (int mf = 0; mf < 4; mf++)
#pragma unroll
            for (int nf = 0; nf < 4; nf++) {
                const int row0 = tm * 128 + wr * 64 + mf * 16 + g4 * 4;
                const int col = tn * 128 + wc * 64 + nf * 16 + c15;
#pragma unroll
                for (int r = 0; r < 4; r++) C[(size_t)(row0 + r) * 4096 + col] = zz_f2bf(acc[mf][nf][r]);
            }
    } else {
        const int tm = bx >> 4, tn = bx & 15;  // 4096 x 2048
        zz_gemm128(Pc, 0, xc, xOff, 512, 512, 512, tm, tn, As, Bs, acc);
#pragma unroll
        for (int mf = 0; mf < 4; mf++)
#pragma unroll
            for (int nf = 0; nf < 4; nf++) {
                const int row0 = tm * 128 + wr * 64 + mf * 16 + g4 * 4;
                const int col = tn * 128 + wc * 64 + nf * 16 + c15;
#pragma unroll
                for (int r = 0; r < 4; r++) Vt[(size_t)(row0 + r) * 2048 + col] = zz_f2bf(acc[mf][nf][r]);
            }
    }
}

// ---------------- QK^T: lower-triangle tiles only (triangular linear grid) ----------------
__global__ __launch_bounds__(256) void zk26_qk(const u16* __restrict__ QZ, const u16* __restrict__ KZ,
                                               u16* __restrict__ Sp, int g0) {
    const int g = blockIdx.y;
    const int head = g0 + g;
    // triangular decode: bx -> (tm, tn), tn <= tm, 136 tiles
    int bx = blockIdx.x;
    int tm = (int)((sqrtf(8.f * (float)bx + 1.f) - 1.f) * 0.5f);
    while ((tm + 1) * (tm + 2) / 2 <= bx) tm++;
    while (tm * (tm + 1) / 2 > bx) tm--;
    const int tn = bx - tm * (tm + 1) / 2;

    __shared__ u16 As[128 * 32];
    __shared__ u16 Bs[128 * 32];

    f32x4 acc[4][4];
    const f32x4 zf = {0.f, 0.f, 0.f, 0.f};
#pragma unroll
    for (int i = 0; i < 4; i++)
#pragma unroll
        for (int j = 0; j < 4; j++) acc[i][j] = zf;

    zz_gemm128(QZ, (size_t)head * 512, KZ, (size_t)head * 512, 512, 4096, 4096, tm, tn, As, Bs, acc);

    const int lane = threadIdx.x & 63;
    const int wid = threadIdx.x >> 6;
    const int wr = wid >> 1, wc = wid & 1;
    const int c15 = lane & 15, g4 = lane >> 4;
    u16* Sg = Sp + (size_t)g * 2048 * 2048;
#pragma unroll
    for (int mf = 0; mf < 4; mf++)
#pragma unroll
        for (int nf = 0; nf < 4; nf++) {
            const int row0 = tm * 128 + wr * 64 + mf * 16 + g4 * 4;
            const int col = tn * 128 + wc * 64 + nf * 16 + c15;
#pragma unroll
            for (int r = 0; r < 4; r++) Sg[(size_t)(row0 + r) * 2048 + col] = zz_f2bf(acc[mf][nf][r]);
        }
}

// ---------------- causal row softmax, in place; masked loads/stores ----------------
__global__ __launch_bounds__(256) void zk26_sm(u16* __restrict__ Sp) {
    const int g = blockIdx.y;
    const int wid = threadIdx.x >> 6, lane = threadIdx.x & 63;
    const int t = blockIdx.x * 4 + wid;
    u16* rowp = Sp + (size_t)g * 2048 * 2048 + (size_t)t * 2048 + lane * 32;
    const float SCL2 = 0.06375826722338107f;  // (1/sqrt(512)) * log2(e)
    const bool doRead = (lane * 32 <= t);
    u16x8 raw[4] = {};
    if (doRead) {
#pragma unroll
        for (int i = 0; i < 4; i++) raw[i] = *(const u16x8*)(rowp + i * 8);
    }
    float v[32];
    float mx = -INFINITY;
#pragma unroll
    for (int i = 0; i < 32; i++) {
        const int s = lane * 32 + i;
        v[i] = (s <= t) ? zz_bf2f(raw[i >> 3][i & 7]) * SCL2 : -INFINITY;
        mx = fmaxf(mx, v[i]);
    }
#pragma unroll
    for (int d = 1; d < 64; d <<= 1) mx = fmaxf(mx, __shfl_xor(mx, d));
    float p[32];
    float sum = 0.f;
#pragma unroll
    for (int i = 0; i < 32; i++) {
        p[i] = exp2f(v[i] - mx);
        sum += p[i];
    }
#pragma unroll
    for (int d = 1; d < 64; d <<= 1) sum += __shfl_xor(sum, d);
    const float inv = 1.f / sum;
    // pv reads cols < ((t>>7)+1)*128 = (t|127)+1; only those need defined (zero) values
    if (lane * 32 <= (t | 127)) {
#pragma unroll
        for (int i = 0; i < 4; i++) {
            u16x8 o;
#pragma unroll
            for (int j = 0; j < 8; j++) o[j] = zz_f2bf(p[i * 8 + j] * inv);
            *(u16x8*)(rowp + i * 8) = o;
        }
    }
}

// ---------------- PV: Oc cols (g0+g)*512.. = Sp[g] @ Vtall-slice^T, K truncated ----------------
__global__ __launch_bounds__(256) void zk26_pv(const u16* __restrict__ Sp, const u16* __restrict__ Vt,
                                               u16* __restrict__ Oc, int g0) {
    __shared__ u16 As[128 * 32];
    __shared__ u16 Bs[128 * 32];
    const int g = blockIdx.y;
    const int bx = blockIdx.x;
    const int tm = bx >> 2, tn = bx & 3;
    const int K = (tm + 1) * 128;

    f32x4 acc[4][4];
    const f32x4 zf = {0.f, 0.f, 0.f, 0.f};
#pragma unroll
    for (int i = 0; i < 4; i++)
#pragma unroll
        for (int j = 0; j < 4; j++) acc[i][j] = zf;

    zz_gemm128(Sp, (size_t)g * 2048 * 2048, Vt, (size_t)(g0 + g) * 512 * 2048, K, 2048, 2048, tm, tn,
               As, Bs, acc);

    const int lane = threadIdx.x & 63;
    const int wid = threadIdx.x >> 6;
    const int wr = wid >> 1, wc = wid & 1;
    const int c15 = lane & 15, g4 = lane >> 4;
    u16* Ob = Oc + (size_t)(g0 + g) * 512;
#pragma unroll
    for (int mf = 0; mf < 4; mf++)
#pragma unroll
        for (int nf = 0; nf < 4; nf++) {
            const int row0 = tm * 128 + wr * 64 + mf * 16 + g4 * 4;
            const int col = tn * 128 + wc * 64 + nf * 16 + c15;
#pragma unroll
            for (int r = 0; r < 4; r++) Ob[(size_t)(row0 + r) * 4096 + col] = zz_f2bf(acc[mf][nf][r]);
        }
}

// ---------------- output projection, split-K=4 ----------------
__global__ __launch_bounds__(256) void zk26_oproj(const u16* __restrict__ Oc, const u16* __restrict__ Woc,
                                                  float* __restrict__ y4) {
    __shared__ u16 As[128 * 32];
    __shared__ u16 Bs[128 * 32];
    const int s = blockIdx.y;
    const int bx = blockIdx.x;
    const int tm = bx >> 2, tn = bx & 3;

    f32x4 acc[4][4];
    const f32x4 zf = {0.f, 0.f, 0.f, 0.f};
#pragma unroll
    for (int i = 0; i < 4; i++)
#pragma unroll
        for (int j = 0; j < 4; j++) acc[i][j] = zf;

    zz_gemm128(Oc, (size_t)s * 1024, Woc, (size_t)s * 1024, 1024, 4096, 4096, tm, tn, As, Bs, acc);

    const int lane = threadIdx.x & 63;
    const int wid = threadIdx.x >> 6;
    const int wr = wid >> 1, wc = wid & 1;
    const int c15 = lane & 15, g4 = lane >> 4;
    float* yb = y4 + (size_t)s * 2048 * 512;
#pragma unroll
    for (int mf = 0; mf < 4; mf++)
#pragma unroll
        for (int nf = 0; nf < 4; nf++) {
            const int row0 = tm * 128 + wr * 64 + mf * 16 + g4 * 4;
            const int col = tn * 128 + wc * 64 + nf * 16 + c15;
#pragma unroll
            for (int r = 0; r < 4; r++) yb[(size_t)(row0 + r) * 512 + col] = acc[mf][nf][r];
        }
}

// ---------------- bias + residual + LN; sums 4 partials; fp32 x residual ----------------
__global__ __launch_bounds__(256) void zk26_ln(const float* __restrict__ y4, const void* __restrict__ x,
                                               int b, const void* __restrict__ bo,
                                               const void* __restrict__ ga, const void* __restrict__ be,
                                               void* __restrict__ outbase) {
    const bool isf = zz_isf(x);
    const int wid = threadIdx.x >> 6, lane = threadIdx.x & 63;
    const int row = blockIdx.x * 4 + wid;
    const size_t grow = (size_t)b * 2048 + row;
    const int d0 = lane * 8;
    f8 xv = zz_ld8f(x, grow * 512 + d0, isf);
    f8 bov = zz_ld8f(bo, d0, isf);
    float h[8];
#pragma unroll
    for (int j = 0; j < 8; j++) h[j] = bov.v[j] + xv.v[j];
#pragma unroll
    for (int s = 0; s < 4; s++) {
        const float* yp = y4 + (size_t)s * 2048 * 512 + (size_t)row * 512 + d0;
        f32x4 a0 = *(const f32x4*)(yp);
        f32x4 a1 = *(const f32x4*)(yp + 4);
#pragma unroll
        for (int j = 0; j < 4; j++) {
            h[j] += a0[j];
            h[4 + j] += a1[j];
        }
    }
    float sum = 0.f, sq = 0.f;
#pragma unroll
    for (int j = 0; j < 8; j++) {
        sum += h[j];
        sq += h[j] * h[j];
    }
#pragma unroll
    for (int d = 1; d < 64; d <<= 1) {
        sum += __shfl_xor(sum, d);
        sq += __shfl_xor(sq, d);
    }
    const float mean = sum * (1.f / 512.f);
    const float var = sq * (1.f / 512.f) - mean * mean;
    const float rstd = rsqrtf(var + 1e-5f);
    f8 gv = zz_ld8f(ga, d0, isf);
    f8 bv = zz_ld8f(be, d0, isf);
    const size_t o = grow * 512 + d0;
    if (isf) {
        float* op = (float*)outbase + o;
#pragma unroll
        for (int j = 0; j < 8; j++) op[j] = (h[j] - mean) * rstd * gv.v[j] + bv.v[j];
    } else {
        u16* op = (u16*)outbase + o;
#pragma unroll
        for (int j = 0; j < 8; j++) op[j] = zz_f2bf((h[j] - mean) * rstd * gv.v[j] + bv.v[j]);
    }
}

__global__ __launch_bounds__(256) void zk26_band(float* __restrict__ out, float val) {
    const size_t gid = (size_t)blockIdx.x * 256 + threadIdx.x;
    float* p = out + gid * 8;
#pragma unroll
    for (int j = 0; j < 8; j++) p[j] = val;
}

extern "C" void kernel_launch(void* const* d_in, const int* in_sizes, int n_in, void* d_out,
                              int out_size, void* d_ws, size_t ws_size, hipStream_t stream) {
    if (n_in != 8 || in_sizes[0] != 4194304 || in_sizes[5] != 512) {
        zk26_band<<<dim3(2048), dim3(256), 0, stream>>>((float*)d_out, 16.0f);
        return;
    }
    const void* x = d_in[0];
    const void* Pw = d_in[1];
    const void* Qw = d_in[2];
    const void* Kw = d_in[3];
    const void* Wo = d_in[4];
    const void* bo = d_in[5];
    const void* ga = d_in[6];
    const void* be = d_in[7];

    // ws: conv 25.2MB + QZall/KZall/Vtall 48MB + Sp G*8MB + Oc 16MB.  y4 (16MB) aliases Sp.
    const size_t convB = 2 * (256 + 4194304 + 4 * 2097152);
    auto need = [&](int g) -> size_t {
        return convB + 3 * (size_t)2048 * 4096 * 2 + (size_t)g * 2048 * 2048 * 2 +
               (size_t)2048 * 4096 * 2;
    };
    int G = 4;
    if (ws_size >= need(8)) G = 8;

    u16* xc = (u16*)d_ws + 256;
    u16* Pc = xc + 4194304;
    u16* Qc = Pc + 2097152;
    u16* Kc = Qc + 2097152;
    u16* Woc = Kc + 2097152;
    u16* QZ = Woc + 2097152;                   // 2048 x 4096
    u16* KZ = QZ + (size_t)2048 * 4096;        // 2048 x 4096
    u16* Vt = KZ + (size_t)2048 * 4096;        // 4096 x 2048
    u16* Sp = Vt + (size_t)4096 * 2048;        // G x 2048 x 2048
    u16* Oc = Sp + (size_t)G * 2048 * 2048;    // 2048 x 4096
    float* y4 = (float*)Sp;                    // 4 x 2048 x 512 fp32, aliases Sp

    zk26_conv<<<dim3(2048, 5), dim3(256), 0, stream>>>(x, Pw, Qw, Kw, Wo, xc, Pc, Qc, Kc, Woc);

    for (int b = 0; b < 4; b++) {
        zk26_proj<<<dim3(512, 3), dim3(256), 0, stream>>>(xc, b, Qc, Kc, Pc, QZ, KZ, Vt);
        for (int g0 = 0; g0 < 8; g0 += G) {
            zk26_qk<<<dim3(136, G), dim3(256), 0, stream>>>(QZ, KZ, Sp, g0);
            zk26_sm<<<dim3(512, G), dim3(256), 0, stream>>>(Sp);
            zk26_pv<<<dim3(64, G), dim3(256), 0, stream>>>(Sp, Vt, Oc, g0);
        }
        zk26_oproj<<<dim3(64, 4), dim3(256), 0, stream>>>(Oc, Woc, y4);
        zk26_ln<<<dim3(512), dim3(256), 0, stream>>>(y4, x, b, bo, ga, be, d_out);
    }
}